// Round 5
// baseline (18.219 us; speedup 1.0000x reference)
//
#include <hip/hip_runtime.h>

// Reference collapses: softmax over singleton axis => weights == 1.
// out[b, g*M+m, h, w] = 7x7 box sum of v,  v = grouped 1x1 conv(x, Wv).
// Separable + linear: vertical 7-tap FIRST (per-thread sliding sum in regs),
// stage vp in LDS; then horizontal 7-tap (3x ds_read_b128 + running sum)
// fused with the Wv mix, float4 stores.
//
// R5: P1 now uses ALL 256 threads (R4 idled half). Each column's 8 vp rows
// are split across two threads (10 loads each, 6-row overlap -> L2 hits):
// serial chain 14->10 loads, 2x VMEM issue parallelism in P1.

#define TH   8           // output rows per block
#define HALO 3
#define WID  64
#define HGT  64
#define NG   8
#define NM   8
#define NC   8
#define NTILE (HGT / TH) // 8
#define NBG  64          // B*G
#define VPS  72          // vp row stride: 4 zero-pad | 64 | 4 zero-pad

typedef float f4 __attribute__((ext_vector_type(4)));

__global__ __launch_bounds__(256)
void mhsa_boxsum_kernel(const float* __restrict__ x,
                        const float* __restrict__ Wv,
                        float* __restrict__ out) {
    __shared__ float vp[NC * TH * VPS];   // 18432 B
    __shared__ float wv_s[NM * NC];

    // bijective XCD-aware decode: all 8 tiles of a (b,g) on one XCD
    const int lb   = (int)blockIdx.x;     // 0..511
    const int xcd  = lb & 7;
    const int ix   = lb >> 3;             // 0..63
    const int bg   = xcd * 8 + (ix >> 3); // 0..63
    const int tile = ix & 7;              // 0..7
    const int r0   = tile * TH;

    const int tid  = (int)threadIdx.x;
    const int g    = bg & (NG - 1);
    if (tid < NM * NC) wv_s[tid] = Wv[g * (NM * NC) + tid];

    const float* xbase = x + (size_t)bg * NC * HGT * WID;

    // ---- P1: vertical 7-tap, all 256 threads ----
    // thread -> (half, c8, q): half picks vp rows 0-3 or 4-7 of this tile.
    {
        const int half = tid >> 7;        // 0 or 1
        const int c8   = (tid >> 4) & 7;
        const int q    = tid & 15;        // w = 4q..4q+3
        const int rb   = half * 4;        // first vp row this thread produces
        f4 a[10];
        #pragma unroll
        for (int j = 0; j < 10; ++j) {
            const int gr = r0 - HALO + rb + j;
            f4 t = {0.f, 0.f, 0.f, 0.f};
            if (gr >= 0 && gr < HGT)
                t = *(const f4*)(xbase + ((size_t)(c8 * HGT + gr)) * WID + q * 4);
            a[j] = t;
        }
        f4 s = a[0];
        #pragma unroll
        for (int j = 1; j < 7; ++j) s += a[j];
        *(f4*)(&vp[(c8 * TH + rb) * VPS + 4 + q * 4]) = s;
        #pragma unroll
        for (int r = 1; r < 4; ++r) {
            s += a[r + 6] - a[r - 1];
            *(f4*)(&vp[(c8 * TH + rb + r) * VPS + 4 + q * 4]) = s;
        }
        // zero the left/right pads: 128 f4 slots, threads 0..127
        if (tid < 128) {
            const int side = tid & 1;
            const int r    = (tid >> 1) & 7;
            const int pc8  = tid >> 4;
            *(f4*)(&vp[(pc8 * TH + r) * VPS + side * 68]) = (f4){0.f, 0.f, 0.f, 0.f};
        }
    }
    __syncthreads();

    // ---- P2: horizontal 7-tap running sum + Wv mix; thread = (q, r, mh) ----
    const int qr = tid & 127;
    const int mh = tid >> 7;              // 0: m 0-3, 1: m 4-7
    const int q  = qr & 15;
    const int r  = qr >> 4;               // 0..7

    f4 w0[4], w1[4];
    #pragma unroll
    for (int mi = 0; mi < 4; ++mi) {
        w0[mi] = *(const f4*)&wv_s[(mh * 4 + mi) * 8 + 0];
        w1[mi] = *(const f4*)&wv_s[(mh * 4 + mi) * 8 + 4];
    }

    f4 acc[4];
    #pragma unroll
    for (int mi = 0; mi < 4; ++mi) acc[mi] = (f4){0.f, 0.f, 0.f, 0.f};

    #pragma unroll
    for (int c8 = 0; c8 < NC; ++c8) {
        const float* row = &vp[(c8 * TH + r) * VPS + q * 4];
        f4 L = *(const f4*)(row);        // w-4..w-1 (pad-zeroed at q==0)
        f4 M = *(const f4*)(row + 4);    // w  ..w+3
        f4 R = *(const f4*)(row + 8);    // w+4..w+7 (pad-zeroed at q==15)
        const float t  = (L.y + L.z) + L.w;
        const float sM = (M.x + M.y) + (M.z + M.w);
        f4 hb;
        hb.x = t + sM;
        hb.y = hb.x - L.y + R.x;
        hb.z = hb.y - L.z + R.y;
        hb.w = hb.z - L.w + R.z;
        #pragma unroll
        for (int mi = 0; mi < 4; ++mi) {
            const float wv = (c8 < 4) ? w0[mi][c8] : w1[mi][c8 - 4];
            acc[mi] += hb * wv;
        }
    }

    float* obase = out + (size_t)bg * NM * HGT * WID;
    #pragma unroll
    for (int mi = 0; mi < 4; ++mi) {
        const int m = mh * 4 + mi;
        *(f4*)(obase + ((size_t)(m * HGT + r0 + r)) * WID + q * 4) = acc[mi];
    }
}

extern "C" void kernel_launch(void* const* d_in, const int* in_sizes, int n_in,
                              void* d_out, int out_size, void* d_ws, size_t ws_size,
                              hipStream_t stream) {
    const float* x  = (const float*)d_in[0];
    // d_in[1] = Wq, d_in[2] = Wk  -- dead (softmax over singleton axis == 1)
    const float* Wv = (const float*)d_in[3];
    float* out = (float*)d_out;

    dim3 grid(NTILE * NBG);   // 512 blocks
    dim3 block(256);
    mhsa_boxsum_kernel<<<grid, block, 0, stream>>>(x, Wv, out);
}

// Round 6
// 9.894 us; speedup vs baseline: 1.8415x; 1.8415x over previous
//
#include <hip/hip_runtime.h>

// Reference collapses: softmax over singleton axis => weights == 1.
// out[b, g*M+m, h, w] = 7x7 box sum of v,  v = grouped 1x1 conv(x, Wv).
// Separable + linear: vertical 7-tap FIRST (per-thread sliding sum in regs),
// stage vp in LDS; then horizontal 7-tap (3x ds_read_b128 + running sum)
// fused with the Wv mix, float4 stores.
//
// R6: revert to R4 structure (best: 10.42 us; R5's all-thread P1 regressed to
// 18.2 -- more loads + deeper serial chains). Add nontemporal output stores
// (out is write-once; keep x halo lines in L2). R3/R4 identical at ~10.4 us
// across major structural change => measurement floor ~= replay overhead +
// compulsory traffic; expect ~10.4 again, then declare roofline.

#define TH   8           // output rows per block
#define HALO 3
#define LR   (TH + 6)    // 14 loaded rows
#define WID  64
#define HGT  64
#define NG   8
#define NM   8
#define NC   8
#define NTILE (HGT / TH) // 8
#define NBG  64          // B*G
#define VPS  72          // vp row stride: 4 zero-pad | 64 | 4 zero-pad

typedef float f4 __attribute__((ext_vector_type(4)));

__global__ __launch_bounds__(256)
void mhsa_boxsum_kernel(const float* __restrict__ x,
                        const float* __restrict__ Wv,
                        float* __restrict__ out) {
    __shared__ float vp[NC * TH * VPS];   // 18432 B
    __shared__ float wv_s[NM * NC];

    // bijective XCD-aware decode: all 8 tiles of a (b,g) on one XCD
    const int lb   = (int)blockIdx.x;     // 0..511
    const int xcd  = lb & 7;
    const int ix   = lb >> 3;             // 0..63
    const int bg   = xcd * 8 + (ix >> 3); // 0..63
    const int tile = ix & 7;              // 0..7
    const int r0   = tile * TH;

    const int tid  = (int)threadIdx.x;
    const int g    = bg & (NG - 1);
    if (tid < NM * NC) wv_s[tid] = Wv[g * (NM * NC) + tid];

    const float* xbase = x + (size_t)bg * NC * HGT * WID;

    if (tid < NC * 16) {
        // ---- P1 (threads 0..127): vertical 7-tap sliding sum, regs only ----
        const int c8 = tid >> 4;
        const int q  = tid & 15;          // w = 4q..4q+3
        f4 a[LR];
        #pragma unroll
        for (int j = 0; j < LR; ++j) {
            const int gr = r0 - HALO + j;
            f4 t = {0.f, 0.f, 0.f, 0.f};
            if (gr >= 0 && gr < HGT)
                t = *(const f4*)(xbase + ((size_t)(c8 * HGT + gr)) * WID + q * 4);
            a[j] = t;
        }
        f4 s = a[0];
        #pragma unroll
        for (int j = 1; j < 7; ++j) s += a[j];
        *(f4*)(&vp[(c8 * TH + 0) * VPS + 4 + q * 4]) = s;
        #pragma unroll
        for (int r = 1; r < TH; ++r) {
            s += a[r + 6] - a[r - 1];
            *(f4*)(&vp[(c8 * TH + r) * VPS + 4 + q * 4]) = s;
        }
    } else {
        // ---- threads 128..255: zero the left/right pads (128 f4 slots) ----
        const int p    = tid - 128;       // 0..127
        const int side = p & 1;
        const int r    = (p >> 1) & 7;
        const int c8   = p >> 4;
        *(f4*)(&vp[(c8 * TH + r) * VPS + side * 68]) = (f4){0.f, 0.f, 0.f, 0.f};
    }
    __syncthreads();

    // ---- P2: horizontal 7-tap running sum + Wv mix; thread = (q, r, mh) ----
    const int qr = tid & 127;
    const int mh = tid >> 7;              // 0: m 0-3, 1: m 4-7
    const int q  = qr & 15;
    const int r  = qr >> 4;               // 0..7

    f4 w0[4], w1[4];
    #pragma unroll
    for (int mi = 0; mi < 4; ++mi) {
        w0[mi] = *(const f4*)&wv_s[(mh * 4 + mi) * 8 + 0];
        w1[mi] = *(const f4*)&wv_s[(mh * 4 + mi) * 8 + 4];
    }

    f4 acc[4];
    #pragma unroll
    for (int mi = 0; mi < 4; ++mi) acc[mi] = (f4){0.f, 0.f, 0.f, 0.f};

    #pragma unroll
    for (int c8 = 0; c8 < NC; ++c8) {
        const float* row = &vp[(c8 * TH + r) * VPS + q * 4];
        f4 L = *(const f4*)(row);        // w-4..w-1 (pad-zeroed at q==0)
        f4 M = *(const f4*)(row + 4);    // w  ..w+3
        f4 R = *(const f4*)(row + 8);    // w+4..w+7 (pad-zeroed at q==15)
        const float t  = (L.y + L.z) + L.w;
        const float sM = (M.x + M.y) + (M.z + M.w);
        f4 hb;
        hb.x = t + sM;
        hb.y = hb.x - L.y + R.x;
        hb.z = hb.y - L.z + R.y;
        hb.w = hb.z - L.w + R.z;
        #pragma unroll
        for (int mi = 0; mi < 4; ++mi) {
            const float wv = (c8 < 4) ? w0[mi][c8] : w1[mi][c8 - 4];
            acc[mi] += hb * wv;
        }
    }

    float* obase = out + (size_t)bg * NM * HGT * WID;
    #pragma unroll
    for (int mi = 0; mi < 4; ++mi) {
        const int m = mh * 4 + mi;
        __builtin_nontemporal_store(acc[mi],
            (f4*)(obase + ((size_t)(m * HGT + r0 + r)) * WID + q * 4));
    }
}

extern "C" void kernel_launch(void* const* d_in, const int* in_sizes, int n_in,
                              void* d_out, int out_size, void* d_ws, size_t ws_size,
                              hipStream_t stream) {
    const float* x  = (const float*)d_in[0];
    // d_in[1] = Wq, d_in[2] = Wk  -- dead (softmax over singleton axis == 1)
    const float* Wv = (const float*)d_in[3];
    float* out = (float*)d_out;

    dim3 grid(NTILE * NBG);   // 512 blocks
    dim3 block(256);
    mhsa_boxsum_kernel<<<grid, block, 0, stream>>>(x, Wv, out);
}